// Round 16
// baseline (411.854 us; speedup 1.0000x reference)
//
#include <hip/hip_runtime.h>
#include <hip/hip_bf16.h>
#include <stdint.h>

typedef __bf16 bf16;
typedef __bf16 bf16x8 __attribute__((ext_vector_type(8)));
typedef __bf16 bf16x4 __attribute__((ext_vector_type(4)));
typedef float f32x4 __attribute__((ext_vector_type(4)));
typedef unsigned short u16;

__device__ __forceinline__ void gload_lds16(const bf16* g, bf16* l) {
    __builtin_amdgcn_global_load_lds(
        (const __attribute__((address_space(1))) void*)g,
        (__attribute__((address_space(3))) void*)l, 16, 0, 0);
}

// One 16B staging chunk: XOR-swizzled global source, linear LDS dest.
__device__ __forceinline__ void stChunk(const bf16* __restrict__ g, int ld,
                                        bf16* l, int c) {
    int row = c >> 3, slot = c & 7;
    gload_lds16(g + (size_t)row * ld + ((slot ^ (row & 7)) << 3), l + c * 8);
}
// A: 128x64 tile, 1024 chunks, 4/thread.  B: 64x64 tile, 512 chunks, 2/thread.
__device__ __forceinline__ void stageA4(const bf16* __restrict__ g, int lda,
                                        bf16* l, int t) {
#pragma unroll
    for (int i = 0; i < 4; ++i) stChunk(g, lda, l, (i << 8) + t);
}
__device__ __forceinline__ void stageB2(const bf16* __restrict__ g, int ldb,
                                        bf16* l, int t) {
#pragma unroll
    for (int i = 0; i < 2; ++i) stChunk(g, ldb, l, (i << 8) + t);
}

// Swizzled LDS fragment read: row-major [rows][64] bf16, kc = 16B slot 0..7.
#define LDSW(buf, row, kc) \
    (*(const bf16x8*)&(buf)[(row) * 64 + ((((kc) ^ ((row) & 7))) << 3)])

// 128x64 wave-tile MMA: wave wv owns rows [wv*32, wv*32+32), all 64 cols.
__device__ __forceinline__ void mma_tile(const bf16* A, const bf16* B,
                                         f32x4 acc[2][4], int lane, int wv) {
    const int r0 = wv * 32 + (lane & 15);
    const int kq = lane >> 4;
    bf16x8 a[2][2], b[4][2];
#pragma unroll
    for (int mi = 0; mi < 2; ++mi) {
        int rA = r0 + mi * 16;
#pragma unroll
        for (int kk = 0; kk < 2; ++kk) a[mi][kk] = LDSW(A, rA, kk * 4 + kq);
    }
#pragma unroll
    for (int ni = 0; ni < 4; ++ni) {
        int rB = ni * 16 + (lane & 15);
#pragma unroll
        for (int kk = 0; kk < 2; ++kk) b[ni][kk] = LDSW(B, rB, kk * 4 + kq);
    }
#pragma unroll
    for (int kk = 0; kk < 2; ++kk)
#pragma unroll
        for (int mi = 0; mi < 2; ++mi)
#pragma unroll
            for (int ni = 0; ni < 4; ++ni)
                acc[mi][ni] = __builtin_amdgcn_mfma_f32_16x16x32_bf16(
                    a[mi][kk], b[ni][kk], acc[mi][ni], 0, 0, 0);
}

// ---------- prep kernels ----------
__global__ void prep_alpha(const float* __restrict__ a, float* __restrict__ out) {
    int i = blockIdx.x * blockDim.x + threadIdx.x;
    if (i < 1024) out[i] = 0.5f / (1.0f + __expf(-a[i]));
}

__global__ void prep_adj(const float* __restrict__ adj, const float* __restrict__ ahs,
                         bf16* __restrict__ adjb) {
    int i = blockIdx.x * blockDim.x + threadIdx.x;
    int row = i >> 8;
    float s = ahs[row];
    float4 v = ((const float4*)adj)[i];
    bf16x4 o = {(bf16)(s * v.x), (bf16)(s * v.y), (bf16)(s * v.z), (bf16)(s * v.w)};
    ((bf16x4*)adjb)[i] = o;
}

__global__ void cast_f32_bf16x4(const float* __restrict__ src, bf16* __restrict__ dst,
                                int n4) {
    int i = blockIdx.x * blockDim.x + threadIdx.x;
    if (i < n4) {
        float4 v = ((const float4*)src)[i];
        bf16x4 o = {(bf16)v.x, (bf16)v.y, (bf16)v.z, (bf16)v.w};
        ((bf16x4*)dst)[i] = o;
    }
}

__global__ void prep_weff(const float* __restrict__ w, const float* __restrict__ dv,
                          bf16* __restrict__ weffT) {
    __shared__ float wk[256];
    __shared__ float dd[256];
    int k = blockIdx.x, j = threadIdx.x;
    dd[j] = fminf(fmaxf(dv[j], 0.0f), 1.0f);
    wk[j] = w[k * 256 + j];
    __syncthreads();
    float s = 0.0f;
#pragma unroll 8
    for (int c = 0; c < 256; ++c) s += wk[c] * dd[c] * w[j * 256 + c];
    weffT[j * 256 + k] = (bf16)s;
}

// xT[b][d][n] = bf16(x[b][n][d]); also xb[b][n][d] = bf16(x) in the same pass.
__global__ void prep_xT(const float* __restrict__ x, bf16* __restrict__ xT,
                        bf16* __restrict__ xb) {
    __shared__ bf16 tile[64][65];
    int b = blockIdx.z, n0 = blockIdx.x * 64, d0 = blockIdx.y * 64;
    int t = threadIdx.x;
    int i = t >> 4, j4 = (t & 15) * 4;
#pragma unroll
    for (int p = 0; p < 4; ++p) {
        int n = i + p * 16;
        size_t gi = (((size_t)b << 10) + n0 + n) * 256 + d0 + j4;
        float4 v = *(const float4*)&x[gi];
        bf16x4 o = {(bf16)v.x, (bf16)v.y, (bf16)v.z, (bf16)v.w};
        *(bf16x4*)&xb[gi] = o;
        tile[n][j4 + 0] = o[0]; tile[n][j4 + 1] = o[1];
        tile[n][j4 + 2] = o[2]; tile[n][j4 + 3] = o[3];
    }
    __syncthreads();
#pragma unroll
    for (int p = 0; p < 4; ++p) {
        int c = p * 256 + t;
        int d = c >> 4, nc = c & 15;
        bf16x4 o = {tile[nc * 4 + 0][d], tile[nc * 4 + 1][d],
                    tile[nc * 4 + 2][d], tile[nc * 4 + 3][d]};
        *(bf16x4*)&xT[(((size_t)(b * 256 + d0 + d)) << 10) + n0 + nc * 4] = o;
    }
}

// ---------- fc_in GEMM: h0 = x @ fcw^T + b (3-buf pipelined, unchanged) -----
template <int NT, typename F>
__device__ __forceinline__ void run_pipeline(F tadr, bf16 (*As)[8192],
                                             bf16 (*Bs)[4096], f32x4 acc[2][4],
                                             int t, int lane, int wv) {
    {
        const bf16 *Ag, *Bg; int lda, ldb;
        tadr(0, Ag, lda, Bg, ldb);
        stageA4(Ag, lda, As[0], t);
        stageB2(Bg, ldb, Bs[0], t);
        if (NT > 1) {
            tadr(1, Ag, lda, Bg, ldb);
            stageA4(Ag, lda, As[1], t);
            stageB2(Bg, ldb, Bs[1], t);
        }
    }
    int cur = 0, pre = 2;
#pragma unroll 1
    for (int i = 0; i < NT; ++i) {
        if (i + 2 < NT) {
            const bf16 *Ag, *Bg; int lda, ldb;
            tadr(i + 2, Ag, lda, Bg, ldb);
            stageA4(Ag, lda, As[pre], t);
            stageB2(Bg, ldb, Bs[pre], t);
            asm volatile("s_waitcnt vmcnt(12)" ::: "memory");
        } else if (i + 1 < NT) {
            asm volatile("s_waitcnt vmcnt(6)" ::: "memory");
        } else {
            asm volatile("s_waitcnt vmcnt(0)" ::: "memory");
        }
        __builtin_amdgcn_s_barrier();
        mma_tile(As[cur], Bs[cur], acc, lane, wv);
        __builtin_amdgcn_s_barrier();
        cur = (cur == 2) ? 0 : cur + 1;
        pre = (pre == 2) ? 0 : pre + 1;
    }
}

__launch_bounds__(256, 2)
__global__ void gemm_fcin(const bf16* __restrict__ xb, const bf16* __restrict__ fcwb,
                          const float* __restrict__ fcb,
                          bf16* __restrict__ hb, bf16* __restrict__ hT,
                          bf16* __restrict__ hloT) {
    __shared__ __align__(16) bf16 As[3][8192];
    __shared__ __align__(16) bf16 Bs[3][4096];
    int t = threadIdx.x, lane = t & 63, wv = t >> 6;
    int row0 = blockIdx.y * 128;   // flattened b*1024+n
    int col0 = blockIdx.x * 64;
    f32x4 acc[2][4] = {};
    const bf16* Ab = xb + (size_t)row0 * 256;
    const bf16* Bb = fcwb + (size_t)col0 * 256;
    auto tadr = [&](int i, const bf16*& Ag, int& lda, const bf16*& Bg, int& ldb) {
        Ag = Ab + i * 64; lda = 256;
        Bg = Bb + i * 64; ldb = 256;
    };
    run_pipeline<4>(tadr, As, Bs, acc, t, lane, wv);

    int rbase = row0 + wv * 32 + ((lane >> 4) << 2);
    int cbase = col0 + (lane & 15);
#pragma unroll
    for (int mi = 0; mi < 2; ++mi) {
        int rg = rbase + mi * 16;
#pragma unroll
        for (int ni = 0; ni < 4; ++ni) {
            int col = cbase + ni * 16;
            float bias = fcb[col];
            bf16x4 tv, lv;
#pragma unroll
            for (int r = 0; r < 4; ++r) {
                float v = acc[mi][ni][r] + bias;
                size_t idx = (size_t)(rg + r) * 256 + col;
                bf16 hi = (bf16)v;
                hb[idx] = hi;
                tv[r] = hi;
                lv[r] = (bf16)(v - (float)hi);
            }
            int b = rg >> 10, n = rg & 1023;
            size_t tb = (((size_t)(b * 256 + col)) << 10) + n;
            *(bf16x4*)&hT[tb] = tv;
            *(bf16x4*)&hloT[tb] = lv;
        }
    }
}

// -- fused Euler step: 128x64 tile, single-buf 24KB, m97 2-barrier window,
//    grid 1024 -> 4 blocks/CU (16 waves/CU cross-block overlap) --
template <bool LAST>
__launch_bounds__(256, 4)
__global__ void gemm_step(const bf16* __restrict__ adjb, const bf16* __restrict__ hbp,
                          const bf16* __restrict__ hTp, const bf16* __restrict__ weffT,
                          const float* __restrict__ ahs, const bf16* __restrict__ xT,
                          bf16* __restrict__ hloT, bf16* __restrict__ hbn,
                          bf16* __restrict__ hTn, float* __restrict__ out) {
    __shared__ __align__(16) char smem[24576];   // A 16K | B 8K ; epilogue img 17K
    bf16* As = (bf16*)smem;
    bf16* Bs = (bf16*)(smem + 16384);
    int t = threadIdx.x, lane = t & 63, wv = t >> 6;
    // grid 1024 = 32 b x (8 n-tiles x 4 d-tiles); batch keyed to XCD.
    int g = blockIdx.x;
    int xcd = g & 7, rest = g >> 3;          // rest 0..127
    int b = (rest & 3) * 8 + xcd;
    int tile = rest >> 2;                    // 0..31
    int n0 = (tile & 7) * 128;
    int d0 = (tile >> 3) * 64;
    f32x4 acc[2][4] = {};

    const bf16* A1 = adjb + (size_t)n0 * 1024;                // K=1024, 16 tiles
    const bf16* B1 = hTp + ((size_t)(b * 256 + d0)) * 1024;   // 64 d-rows
    const bf16* A2 = hbp + ((size_t)(b * 1024 + n0)) * 256;   // K=256, 4 tiles
    const bf16* B2 = weffT + (size_t)d0 * 256;

#pragma unroll 1
    for (int i = 0; i < 20; ++i) {           // m97 window: stage, drain, 2 bars
        if (i < 16) {
            stageA4(A1 + i * 64, 1024, As, t);
            stageB2(B1 + i * 64, 1024, Bs, t);
        } else {
            stageA4(A2 + (i - 16) * 64, 256, As, t);
            stageB2(B2 + (i - 16) * 64, 256, Bs, t);
        }
        asm volatile("s_waitcnt vmcnt(0)" ::: "memory");
        __builtin_amdgcn_s_barrier();        // tile published
        mma_tile(As, Bs, acc, lane, wv);
        __builtin_amdgcn_s_barrier();        // reads closed, buffer reusable
    }

    // ---------------- epilogue (hT-layout vectorized) ----------------
    const float dt = 0.125f;
    const int l15 = lane & 15;
    const int lq = (lane >> 4) << 2;
    bf16* img = (bf16*)smem;                 // [64 cols][PADN nodes] (16.9 KB)
    const int PADN = 132;
#pragma unroll
    for (int mi = 0; mi < 2; ++mi) {
        int nl = wv * 32 + mi * 16 + lq;     // local node base (x4 aligned)
        int ng = n0 + nl;
        f32x4 av = *(const f32x4*)&ahs[ng];
#pragma unroll
        for (int ni = 0; ni < 4; ++ni) {
            int cl = ni * 16 + l15;          // local col 0..63
            int cg = d0 + cl;
            size_t tb = (((size_t)(b * 256 + cg)) << 10) + ng;
            bf16x4 hp = *(const bf16x4*)&hTp[tb];
            bf16x4 lp = *(const bf16x4*)&hloT[tb];
            bf16x4 xp = *(const bf16x4*)&xT[tb];
            bf16x4 nhi, nlo;
#pragma unroll
            for (int r = 0; r < 4; ++r) {
                float hold = (float)hp[r] + (float)lp[r];
                float f = acc[mi][ni][r] - (av[r] + 1.0f) * hold + (float)xp[r];
                float hv = hold + dt * f;
                if (LAST) {
                    out[(((size_t)b << 10) + ng + r) * 256 + cg] = hv;
                } else {
                    bf16 hi2 = (bf16)hv;
                    nhi[r] = hi2;
                    nlo[r] = (bf16)(hv - (float)hi2);
                }
            }
            if (!LAST) {
                *(bf16x4*)&hTn[tb] = nhi;
                *(bf16x4*)&hloT[tb] = nlo;
                int nsw = nl ^ (((cl >> 3) & 7) << 2);
                *(bf16x4*)&img[cl * PADN + nsw] = nhi;
            }
        }
    }
    if (!LAST) {
        asm volatile("s_waitcnt lgkmcnt(0)" ::: "memory");
        __builtin_amdgcn_s_barrier();
        const u16* imgu = (const u16*)img;
#pragma unroll
        for (int P = 0; P < 4; ++P) {
            int chunk = P * 256 + t;         // 0..1023
            int node = chunk >> 3;           // 0..127
            int c8 = chunk & 7;              // 8-col group 0..7
            u16 v[8];
#pragma unroll
            for (int k = 0; k < 8; ++k) {
                int col = c8 * 8 + k;        // 0..63
                v[k] = imgu[col * PADN + (node ^ (((col >> 3) & 7) << 2))];
            }
            uint4 pk;
            pk.x = v[0] | ((unsigned)v[1] << 16);
            pk.y = v[2] | ((unsigned)v[3] << 16);
            pk.z = v[4] | ((unsigned)v[5] << 16);
            pk.w = v[6] | ((unsigned)v[7] << 16);
            *(uint4*)&hbn[(((size_t)b << 10) + n0 + node) * 256 + d0 + c8 * 8] = pk;
        }
    }
}

extern "C" void kernel_launch(void* const* d_in, const int* in_sizes, int n_in,
                              void* d_out, int out_size, void* d_ws, size_t ws_size,
                              hipStream_t stream) {
    const float* x     = (const float*)d_in[0];
    const float* adj   = (const float*)d_in[1];
    const float* alpha = (const float*)d_in[2];
    const float* w     = (const float*)d_in[3];
    const float* dvec  = (const float*)d_in[4];
    const float* fcw   = (const float*)d_in[5];
    const float* fcb   = (const float*)d_in[6];
    float* out = (float*)d_out;   // fp32 h, written by the LAST step only

    const size_t HB = (size_t)32 * 1024 * 256 * 2;  // 16 MiB
    char* p = (char*)d_ws;
    bf16* hb0   = (bf16*)p; p += HB;
    bf16* hb1   = (bf16*)p; p += HB;
    bf16* hT0   = (bf16*)p; p += HB;
    bf16* hT1   = (bf16*)p; p += HB;
    bf16* xb    = (bf16*)p; p += HB;
    bf16* hloT  = (bf16*)p; p += HB;
    bf16* xT    = (bf16*)p; p += HB;
    bf16* adjb  = (bf16*)p; p += (size_t)1024 * 1024 * 2;
    bf16* fcwb  = (bf16*)p; p += 256 * 256 * 2;
    bf16* weffT = (bf16*)p; p += 256 * 256 * 2;
    float* ahs  = (float*)p; p += 1024 * 4;

    prep_alpha<<<4, 256, 0, stream>>>(alpha, ahs);
    prep_adj<<<1024, 256, 0, stream>>>(adj, ahs, adjb);
    prep_weff<<<256, 256, 0, stream>>>(w, dvec, weffT);
    prep_xT<<<dim3(16, 4, 32), 256, 0, stream>>>(x, xT, xb);
    cast_f32_bf16x4<<<64, 256, 0, stream>>>(fcw, fcwb, 16384);

    gemm_fcin<<<dim3(4, 256), 256, 0, stream>>>(xb, fcwb, fcb, hb0, hT0, hloT);

    bf16* hb[2] = {hb0, hb1};
    bf16* hT[2] = {hT0, hT1};
    int cur = 0;
    for (int s = 0; s < 8; ++s) {
        if (s < 7)
            gemm_step<false><<<1024, 256, 0, stream>>>(
                adjb, hb[cur], hT[cur], weffT, ahs, xT, hloT,
                hb[cur ^ 1], hT[cur ^ 1], out);
        else
            gemm_step<true><<<1024, 256, 0, stream>>>(
                adjb, hb[cur], hT[cur], weffT, ahs, xT, hloT,
                hb[cur ^ 1], hT[cur ^ 1], out);
        cur ^= 1;
    }
}

// Round 18
// 373.145 us; speedup vs baseline: 1.1037x; 1.1037x over previous
//
#include <hip/hip_runtime.h>
#include <hip/hip_bf16.h>
#include <stdint.h>

typedef __bf16 bf16;
typedef __bf16 bf16x8 __attribute__((ext_vector_type(8)));
typedef __bf16 bf16x4 __attribute__((ext_vector_type(4)));
typedef float f32x4 __attribute__((ext_vector_type(4)));
typedef unsigned short u16;

__device__ __forceinline__ void gload_lds16(const bf16* g, bf16* l) {
    __builtin_amdgcn_global_load_lds(
        (const __attribute__((address_space(1))) void*)g,
        (__attribute__((address_space(3))) void*)l, 16, 0, 0);
}

// Stage a 128x64 bf16 tile (row stride LD, compile-time) into LDS.
// XOR-swizzled global source, linear LDS dest; 4 chunks/thread (256 thr).
template <int LD>
__device__ __forceinline__ void stage(const bf16* __restrict__ g, bf16* l, int t) {
    int sw = ((t & 7) ^ ((t >> 3) & 7)) << 3;
    size_t base = (size_t)(t >> 3) * LD + sw;
#pragma unroll
    for (int k = 0; k < 4; ++k)
        gload_lds16(g + base + (size_t)(k * 32) * LD, l + t * 8 + k * 2048);
}

// Swizzled LDS fragment read: row-major [rows][64] bf16, kc = 16B slot 0..7.
#define LDSW(buf, row, kc) \
    (*(const bf16x8*)&(buf)[(row) * 64 + ((((kc) ^ ((row) & 7))) << 3)])

// ---------- prep kernels ----------
__global__ void prep_alpha(const float* __restrict__ a, float* __restrict__ out) {
    int i = blockIdx.x * blockDim.x + threadIdx.x;
    if (i < 1024) out[i] = 0.5f / (1.0f + __expf(-a[i]));
}

__global__ void prep_adj(const float* __restrict__ adj, const float* __restrict__ ahs,
                         bf16* __restrict__ adjb) {
    int i = blockIdx.x * blockDim.x + threadIdx.x;
    int row = i >> 8;
    float s = ahs[row];
    float4 v = ((const float4*)adj)[i];
    bf16x4 o = {(bf16)(s * v.x), (bf16)(s * v.y), (bf16)(s * v.z), (bf16)(s * v.w)};
    ((bf16x4*)adjb)[i] = o;
}

__global__ void cast_f32_bf16x4(const float* __restrict__ src, bf16* __restrict__ dst,
                                int n4) {
    int i = blockIdx.x * blockDim.x + threadIdx.x;
    if (i < n4) {
        float4 v = ((const float4*)src)[i];
        bf16x4 o = {(bf16)v.x, (bf16)v.y, (bf16)v.z, (bf16)v.w};
        ((bf16x4*)dst)[i] = o;
    }
}

__global__ void prep_weff(const float* __restrict__ w, const float* __restrict__ dv,
                          bf16* __restrict__ weffT) {
    __shared__ float wk[256];
    __shared__ float dd[256];
    int k = blockIdx.x, j = threadIdx.x;
    dd[j] = fminf(fmaxf(dv[j], 0.0f), 1.0f);
    wk[j] = w[k * 256 + j];
    __syncthreads();
    float s = 0.0f;
#pragma unroll 8
    for (int c = 0; c < 256; ++c) s += wk[c] * dd[c] * w[j * 256 + c];
    weffT[j * 256 + k] = (bf16)s;
}

// xT[b][d][n] = bf16(x[b][n][d]); also xb[b][n][d] = bf16(x) in the same pass.
__global__ void prep_xT(const float* __restrict__ x, bf16* __restrict__ xT,
                        bf16* __restrict__ xb) {
    __shared__ bf16 tile[64][65];
    int b = blockIdx.z, n0 = blockIdx.x * 64, d0 = blockIdx.y * 64;
    int t = threadIdx.x;
    int i = t >> 4, j4 = (t & 15) * 4;
#pragma unroll
    for (int p = 0; p < 4; ++p) {
        int n = i + p * 16;
        size_t gi = (((size_t)b << 10) + n0 + n) * 256 + d0 + j4;
        float4 v = *(const float4*)&x[gi];
        bf16x4 o = {(bf16)v.x, (bf16)v.y, (bf16)v.z, (bf16)v.w};
        *(bf16x4*)&xb[gi] = o;
        tile[n][j4 + 0] = o[0]; tile[n][j4 + 1] = o[1];
        tile[n][j4 + 2] = o[2]; tile[n][j4 + 3] = o[3];
    }
    __syncthreads();
#pragma unroll
    for (int p = 0; p < 4; ++p) {
        int c = p * 256 + t;
        int d = c >> 4, nc = c & 15;
        bf16x4 o = {tile[nc * 4 + 0][d], tile[nc * 4 + 1][d],
                    tile[nc * 4 + 2][d], tile[nc * 4 + 3][d]};
        *(bf16x4*)&xT[(((size_t)(b * 256 + d0 + d)) << 10) + n0 + nc * 4] = o;
    }
}

// ---------------- fc_in machinery (256 threads, 128x64 tile) ---------------
__device__ __forceinline__ void stChunk(const bf16* __restrict__ g, int ld,
                                        bf16* l, int c) {
    int row = c >> 3, slot = c & 7;
    gload_lds16(g + (size_t)row * ld + ((slot ^ (row & 7)) << 3), l + c * 8);
}
__device__ __forceinline__ void stageA4(const bf16* __restrict__ g, int lda,
                                        bf16* l, int t) {
#pragma unroll
    for (int i = 0; i < 4; ++i) stChunk(g, lda, l, (i << 8) + t);
}
__device__ __forceinline__ void stageB2(const bf16* __restrict__ g, int ldb,
                                        bf16* l, int t) {
#pragma unroll
    for (int i = 0; i < 2; ++i) stChunk(g, ldb, l, (i << 8) + t);
}

__device__ __forceinline__ void mma_tile(const bf16* A, const bf16* B,
                                         f32x4 acc[2][4], int lane, int wv) {
    const int r0 = wv * 32 + (lane & 15);
    const int kq = lane >> 4;
    bf16x8 a[2][2], b[4][2];
#pragma unroll
    for (int mi = 0; mi < 2; ++mi) {
        int rA = r0 + mi * 16;
#pragma unroll
        for (int kk = 0; kk < 2; ++kk) a[mi][kk] = LDSW(A, rA, kk * 4 + kq);
    }
#pragma unroll
    for (int ni = 0; ni < 4; ++ni) {
        int rB = ni * 16 + (lane & 15);
#pragma unroll
        for (int kk = 0; kk < 2; ++kk) b[ni][kk] = LDSW(B, rB, kk * 4 + kq);
    }
#pragma unroll
    for (int kk = 0; kk < 2; ++kk)
#pragma unroll
        for (int mi = 0; mi < 2; ++mi)
#pragma unroll
            for (int ni = 0; ni < 4; ++ni)
                acc[mi][ni] = __builtin_amdgcn_mfma_f32_16x16x32_bf16(
                    a[mi][kk], b[ni][kk], acc[mi][ni], 0, 0, 0);
}

template <int NT, typename F>
__device__ __forceinline__ void run_pipeline(F tadr, bf16 (*As)[8192],
                                             bf16 (*Bs)[4096], f32x4 acc[2][4],
                                             int t, int lane, int wv) {
    {
        const bf16 *Ag, *Bg; int lda, ldb;
        tadr(0, Ag, lda, Bg, ldb);
        stageA4(Ag, lda, As[0], t);
        stageB2(Bg, ldb, Bs[0], t);
        if (NT > 1) {
            tadr(1, Ag, lda, Bg, ldb);
            stageA4(Ag, lda, As[1], t);
            stageB2(Bg, ldb, Bs[1], t);
        }
    }
    int cur = 0, pre = 2;
#pragma unroll 1
    for (int i = 0; i < NT; ++i) {
        if (i + 2 < NT) {
            const bf16 *Ag, *Bg; int lda, ldb;
            tadr(i + 2, Ag, lda, Bg, ldb);
            stageA4(Ag, lda, As[pre], t);
            stageB2(Bg, ldb, Bs[pre], t);
            asm volatile("s_waitcnt vmcnt(12)" ::: "memory");
        } else if (i + 1 < NT) {
            asm volatile("s_waitcnt vmcnt(6)" ::: "memory");
        } else {
            asm volatile("s_waitcnt vmcnt(0)" ::: "memory");
        }
        __builtin_amdgcn_s_barrier();
        __builtin_amdgcn_s_setprio(1);
        mma_tile(As[cur], Bs[cur], acc, lane, wv);
        __builtin_amdgcn_s_setprio(0);
        __builtin_amdgcn_s_barrier();
        cur = (cur == 2) ? 0 : cur + 1;
        pre = (pre == 2) ? 0 : pre + 1;
    }
}

// ---------- fc_in GEMM: h0 = x @ fcw^T + b ----------
__launch_bounds__(256, 2)
__global__ void gemm_fcin(const bf16* __restrict__ xb, const bf16* __restrict__ fcwb,
                          const float* __restrict__ fcb,
                          bf16* __restrict__ hb, bf16* __restrict__ hT,
                          bf16* __restrict__ hloT) {
    __shared__ __align__(16) bf16 As[3][8192];
    __shared__ __align__(16) bf16 Bs[3][4096];
    int t = threadIdx.x, lane = t & 63, wv = t >> 6;
    int row0 = blockIdx.y * 128;   // flattened b*1024+n
    int col0 = blockIdx.x * 64;
    f32x4 acc[2][4] = {};
    const bf16* Ab = xb + (size_t)row0 * 256;
    const bf16* Bb = fcwb + (size_t)col0 * 256;
    auto tadr = [&](int i, const bf16*& Ag, int& lda, const bf16*& Bg, int& ldb) {
        Ag = Ab + i * 64; lda = 256;
        Bg = Bb + i * 64; ldb = 256;
    };
    run_pipeline<4>(tadr, As, Bs, acc, t, lane, wv);

    int rbase = row0 + wv * 32 + ((lane >> 4) << 2);
    int cbase = col0 + (lane & 15);
#pragma unroll
    for (int mi = 0; mi < 2; ++mi) {
        int rg = rbase + mi * 16;
#pragma unroll
        for (int ni = 0; ni < 4; ++ni) {
            int col = cbase + ni * 16;
            float bias = fcb[col];
            bf16x4 tv, lv;
#pragma unroll
            for (int r = 0; r < 4; ++r) {
                float v = acc[mi][ni][r] + bias;
                size_t idx = (size_t)(rg + r) * 256 + col;
                bf16 hi = (bf16)v;
                hb[idx] = hi;
                tv[r] = hi;
                lv[r] = (bf16)(v - (float)hi);
            }
            int b = rg >> 10, n = rg & 1023;
            size_t tb = (((size_t)(b * 256 + col)) << 10) + n;
            *(bf16x4*)&hT[tb] = tv;
            *(bf16x4*)&hloT[tb] = lv;
        }
    }
}

// -- fused Euler step: 128x128, dbuf LDS, one barrier/window, ILP'd MMA --
template <bool LAST>
__launch_bounds__(256, 2)
__global__ void gemm_step(const bf16* __restrict__ adjb, const bf16* __restrict__ hbp,
                          const bf16* __restrict__ hTp, const bf16* __restrict__ weffT,
                          const float* __restrict__ ahs, const bf16* __restrict__ xT,
                          bf16* __restrict__ hloT, bf16* __restrict__ hbn,
                          bf16* __restrict__ hTn, float* __restrict__ out) {
    __shared__ __align__(16) char smem[65536];
    bf16 (*As)[8192] = (bf16(*)[8192])smem;              // 2 x 16 KB
    bf16 (*Bs)[8192] = (bf16(*)[8192])(smem + 32768);    // 2 x 16 KB
    int t = threadIdx.x, lane = t & 63, wv = t >> 6;
    int wm = wv >> 1, wn = wv & 1;
    // grid 512 = 32 b x (8 n-tiles x 2 d-tiles); batch keyed to XCD.
    int g = blockIdx.x;
    int xcd = g & 7, rest = g >> 3;
    int b = (rest & 3) * 8 + xcd;
    int tile = rest >> 2;
    int n0 = (tile & 7) * 128;
    int d0 = (tile >> 3) * 128;
    f32x4 acc[4][4] = {};

    // Anti-phase skew: odd blocks on a CU start ~2K cycles late so the two
    // co-resident blocks stall out-of-phase instead of in lockstep.
    if ((g >> 3) & 1) {
        __builtin_amdgcn_s_sleep(15);
        __builtin_amdgcn_s_sleep(15);
    }

    const bf16* A1 = adjb + (size_t)n0 * 1024;                // K=1024, 16 tiles
    const bf16* B1 = hTp + ((size_t)(b * 256 + d0)) * 1024;
    const bf16* A2 = hbp + ((size_t)(b * 1024 + n0)) * 256;   // K=256, 4 tiles
    const bf16* B2 = weffT + (size_t)d0 * 256;

    const int l15 = lane & 15, kq = lane >> 4;
    int rA[4], rB[4];
#pragma unroll
    for (int j = 0; j < 4; ++j) {
        rA[j] = wm * 64 + j * 16 + l15;
        rB[j] = wn * 64 + j * 16 + l15;
    }

    // prologue: stage tile 0
    stage<1024>(A1, As[0], t);
    stage<1024>(B1, Bs[0], t);

#pragma unroll 1
    for (int i = 0; i < 20; ++i) {
        asm volatile("s_waitcnt vmcnt(0)" ::: "memory");
        __builtin_amdgcn_s_barrier();            // buf[i&1] published; prior
                                                 // reads closed (consumed by MFMA)
        if (i + 1 < 20) {                        // WAR-safe post-barrier staging
            if (i + 1 < 16) {
                stage<1024>(A1 + (i + 1) * 64, As[(i + 1) & 1], t);
                stage<1024>(B1 + (i + 1) * 64, Bs[(i + 1) & 1], t);
            } else {
                stage<256>(A2 + (i - 15) * 64, As[(i + 1) & 1], t);
                stage<256>(B2 + (i - 15) * 64, Bs[(i + 1) & 1], t);
            }
        }
        const bf16* A = As[i & 1];
        const bf16* B = Bs[i & 1];
        // ---- ILP'd MMA: all 16 fragment loads issued before any MFMA ----
        bf16x8 af[8], bg[8];
#pragma unroll
        for (int kk = 0; kk < 2; ++kk) {
            int kc = kk * 4 + kq;
#pragma unroll
            for (int j = 0; j < 4; ++j) bg[kk * 4 + j] = LDSW(B, rB[j], kc);
        }
#pragma unroll
        for (int kk = 0; kk < 2; ++kk) {
            int kc = kk * 4 + kq;
#pragma unroll
            for (int j = 0; j < 4; ++j) af[kk * 4 + j] = LDSW(A, rA[j], kc);
        }
        __builtin_amdgcn_sched_barrier(0);       // loads stay clustered above
#pragma unroll
        for (int kk = 0; kk < 2; ++kk)
#pragma unroll
            for (int mi = 0; mi < 4; ++mi)
#pragma unroll
                for (int ni = 0; ni < 4; ++ni)
                    acc[mi][ni] = __builtin_amdgcn_mfma_f32_16x16x32_bf16(
                        af[kk * 4 + mi], bg[kk * 4 + ni], acc[mi][ni], 0, 0, 0);
    }
    __builtin_amdgcn_s_barrier();                // close last MMA reads before
                                                 // epilogue overlays LDS

    // ---------------- epilogue (hT-layout vectorized) ----------------
    const float dt = 0.125f;
    const int lq = (lane >> 4) << 2;
    bf16* img = (bf16*)smem;            // [128 cols][PADN nodes] overlay (33.8 KB)
    const int PADN = 132;
#pragma unroll
    for (int mi = 0; mi < 4; ++mi) {
        int nl = wm * 64 + mi * 16 + lq;         // local node base (x4 aligned)
        int ng = n0 + nl;
        f32x4 av = *(const f32x4*)&ahs[ng];
#pragma unroll
        for (int ni = 0; ni < 4; ++ni) {
            int cl = wn * 64 + ni * 16 + l15;    // local col
            int cg = d0 + cl;
            size_t tb = (((size_t)(b * 256 + cg)) << 10) + ng;
            bf16x4 hp = *(const bf16x4*)&hTp[tb];
            bf16x4 lp = *(const bf16x4*)&hloT[tb];
            bf16x4 xp = *(const bf16x4*)&xT[tb];
            bf16x4 nhi, nlo;
#pragma unroll
            for (int r = 0; r < 4; ++r) {
                float hold = (float)hp[r] + (float)lp[r];
                float f = acc[mi][ni][r] - (av[r] + 1.0f) * hold + (float)xp[r];
                float hv = hold + dt * f;
                if (LAST) {
                    out[(((size_t)b << 10) + ng + r) * 256 + cg] = hv;
                } else {
                    bf16 hi2 = (bf16)hv;
                    nhi[r] = hi2;
                    nlo[r] = (bf16)(hv - (float)hi2);
                }
            }
            if (!LAST) {
                *(bf16x4*)&hTn[tb] = nhi;
                *(bf16x4*)&hloT[tb] = nlo;
                int nsw = nl ^ (((cl >> 3) & 7) << 2);
                *(bf16x4*)&img[cl * PADN + nsw] = nhi;
            }
        }
    }
    if (!LAST) {
        asm volatile("s_waitcnt lgkmcnt(0)" ::: "memory");
        __builtin_amdgcn_s_barrier();
        const u16* imgu = (const u16*)img;
#pragma unroll
        for (int P = 0; P < 8; ++P) {
            int chunk = P * 256 + t;
            int node = chunk >> 4;       // 0..127
            int c8 = chunk & 15;
            u16 v[8];
#pragma unroll
            for (int k = 0; k < 8; ++k) {
                int col = c8 * 8 + k;
                v[k] = imgu[col * PADN + (node ^ (((col >> 3) & 7) << 2))];
            }
            uint4 pk;
            pk.x = v[0] | ((unsigned)v[1] << 16);
            pk.y = v[2] | ((unsigned)v[3] << 16);
            pk.z = v[4] | ((unsigned)v[5] << 16);
            pk.w = v[6] | ((unsigned)v[7] << 16);
            *(uint4*)&hbn[(((size_t)b << 10) + n0 + node) * 256 + d0 + c8 * 8] = pk;
        }
    }
}

extern "C" void kernel_launch(void* const* d_in, const int* in_sizes, int n_in,
                              void* d_out, int out_size, void* d_ws, size_t ws_size,
                              hipStream_t stream) {
    const float* x     = (const float*)d_in[0];
    const float* adj   = (const float*)d_in[1];
    const float* alpha = (const float*)d_in[2];
    const float* w     = (const float*)d_in[3];
    const float* dvec  = (const float*)d_in[4];
    const float* fcw   = (const float*)d_in[5];
    const float* fcb   = (const float*)d_in[6];
    float* out = (float*)d_out;   // fp32 h, written by the LAST step only

    const size_t HB = (size_t)32 * 1024 * 256 * 2;  // 16 MiB
    char* p = (char*)d_ws;
    bf16* hb0   = (bf16*)p; p += HB;
    bf16* hb1   = (bf16*)p; p += HB;
    bf16* hT0   = (bf16*)p; p += HB;
    bf16* hT1   = (bf16*)p; p += HB;
    bf16* xb    = (bf16*)p; p += HB;
    bf16* hloT  = (bf16*)p; p += HB;
    bf16* xT    = (bf16*)p; p += HB;
    bf16* adjb  = (bf16*)p; p += (size_t)1024 * 1024 * 2;
    bf16* fcwb  = (bf16*)p; p += 256 * 256 * 2;
    bf16* weffT = (bf16*)p; p += 256 * 256 * 2;
    float* ahs  = (float*)p; p += 1024 * 4;

    prep_alpha<<<4, 256, 0, stream>>>(alpha, ahs);
    prep_adj<<<1024, 256, 0, stream>>>(adj, ahs, adjb);
    prep_weff<<<256, 256, 0, stream>>>(w, dvec, weffT);
    prep_xT<<<dim3(16, 4, 32), 256, 0, stream>>>(x, xT, xb);
    cast_f32_bf16x4<<<64, 256, 0, stream>>>(fcw, fcwb, 16384);

    gemm_fcin<<<dim3(4, 256), 256, 0, stream>>>(xb, fcwb, fcb, hb0, hT0, hloT);

    bf16* hb[2] = {hb0, hb1};
    bf16* hT[2] = {hT0, hT1};
    int cur = 0;
    for (int s = 0; s < 8; ++s) {
        if (s < 7)
            gemm_step<false><<<512, 256, 0, stream>>>(
                adjb, hb[cur], hT[cur], weffT, ahs, xT, hloT,
                hb[cur ^ 1], hT[cur ^ 1], out);
        else
            gemm_step<true><<<512, 256, 0, stream>>>(
                adjb, hb[cur], hT[cur], weffT, ahs, xT, hloT,
                hb[cur ^ 1], hT[cur ^ 1], out);
        cur ^= 1;
    }
}

// Round 20
// 371.538 us; speedup vs baseline: 1.1085x; 1.0043x over previous
//
#include <hip/hip_runtime.h>
#include <hip/hip_bf16.h>
#include <stdint.h>

typedef __bf16 bf16;
typedef __bf16 bf16x8 __attribute__((ext_vector_type(8)));
typedef __bf16 bf16x4 __attribute__((ext_vector_type(4)));
typedef float f32x4 __attribute__((ext_vector_type(4)));
typedef unsigned short u16;

__device__ __forceinline__ void gload_lds16(const bf16* g, bf16* l) {
    __builtin_amdgcn_global_load_lds(
        (const __attribute__((address_space(1))) void*)g,
        (__attribute__((address_space(3))) void*)l, 16, 0, 0);
}

// Stage a 128x64 bf16 tile (row stride LD, compile-time) into LDS.
// XOR-swizzled global source, linear LDS dest; 4 chunks/thread (256 thr).
template <int LD>
__device__ __forceinline__ void stage(const bf16* __restrict__ g, bf16* l, int t) {
    int sw = ((t & 7) ^ ((t >> 3) & 7)) << 3;
    size_t base = (size_t)(t >> 3) * LD + sw;
#pragma unroll
    for (int k = 0; k < 4; ++k)
        gload_lds16(g + base + (size_t)(k * 32) * LD, l + t * 8 + k * 2048);
}

// Swizzled LDS fragment read: row-major [rows][64] bf16, kc = 16B slot 0..7.
#define LDSW(buf, row, kc) \
    (*(const bf16x8*)&(buf)[(row) * 64 + ((((kc) ^ ((row) & 7))) << 3)])

// ---------- prep kernels ----------
__global__ void prep_alpha(const float* __restrict__ a, float* __restrict__ out) {
    int i = blockIdx.x * blockDim.x + threadIdx.x;
    if (i < 1024) out[i] = 0.5f / (1.0f + __expf(-a[i]));
}

__global__ void prep_adj(const float* __restrict__ adj, const float* __restrict__ ahs,
                         bf16* __restrict__ adjb) {
    int i = blockIdx.x * blockDim.x + threadIdx.x;
    int row = i >> 8;
    float s = ahs[row];
    float4 v = ((const float4*)adj)[i];
    bf16x4 o = {(bf16)(s * v.x), (bf16)(s * v.y), (bf16)(s * v.z), (bf16)(s * v.w)};
    ((bf16x4*)adjb)[i] = o;
}

__global__ void cast_f32_bf16x4(const float* __restrict__ src, bf16* __restrict__ dst,
                                int n4) {
    int i = blockIdx.x * blockDim.x + threadIdx.x;
    if (i < n4) {
        float4 v = ((const float4*)src)[i];
        bf16x4 o = {(bf16)v.x, (bf16)v.y, (bf16)v.z, (bf16)v.w};
        ((bf16x4*)dst)[i] = o;
    }
}

__global__ void prep_weff(const float* __restrict__ w, const float* __restrict__ dv,
                          bf16* __restrict__ weffT) {
    __shared__ float wk[256];
    __shared__ float dd[256];
    int k = blockIdx.x, j = threadIdx.x;
    dd[j] = fminf(fmaxf(dv[j], 0.0f), 1.0f);
    wk[j] = w[k * 256 + j];
    __syncthreads();
    float s = 0.0f;
#pragma unroll 8
    for (int c = 0; c < 256; ++c) s += wk[c] * dd[c] * w[j * 256 + c];
    weffT[j * 256 + k] = (bf16)s;
}

// xT[b][d][n] = bf16(x[b][n][d]); also xb[b][n][d] = bf16(x) in the same pass.
__global__ void prep_xT(const float* __restrict__ x, bf16* __restrict__ xT,
                        bf16* __restrict__ xb) {
    __shared__ bf16 tile[64][65];
    int b = blockIdx.z, n0 = blockIdx.x * 64, d0 = blockIdx.y * 64;
    int t = threadIdx.x;
    int i = t >> 4, j4 = (t & 15) * 4;
#pragma unroll
    for (int p = 0; p < 4; ++p) {
        int n = i + p * 16;
        size_t gi = (((size_t)b << 10) + n0 + n) * 256 + d0 + j4;
        float4 v = *(const float4*)&x[gi];
        bf16x4 o = {(bf16)v.x, (bf16)v.y, (bf16)v.z, (bf16)v.w};
        *(bf16x4*)&xb[gi] = o;
        tile[n][j4 + 0] = o[0]; tile[n][j4 + 1] = o[1];
        tile[n][j4 + 2] = o[2]; tile[n][j4 + 3] = o[3];
    }
    __syncthreads();
#pragma unroll
    for (int p = 0; p < 4; ++p) {
        int c = p * 256 + t;
        int d = c >> 4, nc = c & 15;
        bf16x4 o = {tile[nc * 4 + 0][d], tile[nc * 4 + 1][d],
                    tile[nc * 4 + 2][d], tile[nc * 4 + 3][d]};
        *(bf16x4*)&xT[(((size_t)(b * 256 + d0 + d)) << 10) + n0 + nc * 4] = o;
    }
}

// ---------------- fc_in machinery (256 threads, 128x64 tile) ---------------
__device__ __forceinline__ void stChunk(const bf16* __restrict__ g, int ld,
                                        bf16* l, int c) {
    int row = c >> 3, slot = c & 7;
    gload_lds16(g + (size_t)row * ld + ((slot ^ (row & 7)) << 3), l + c * 8);
}
__device__ __forceinline__ void stageA4(const bf16* __restrict__ g, int lda,
                                        bf16* l, int t) {
#pragma unroll
    for (int i = 0; i < 4; ++i) stChunk(g, lda, l, (i << 8) + t);
}
__device__ __forceinline__ void stageB2(const bf16* __restrict__ g, int ldb,
                                        bf16* l, int t) {
#pragma unroll
    for (int i = 0; i < 2; ++i) stChunk(g, ldb, l, (i << 8) + t);
}

__device__ __forceinline__ void mma_tile(const bf16* A, const bf16* B,
                                         f32x4 acc[2][4], int lane, int wv) {
    const int r0 = wv * 32 + (lane & 15);
    const int kq = lane >> 4;
    bf16x8 a[2][2], b[4][2];
#pragma unroll
    for (int mi = 0; mi < 2; ++mi) {
        int rA = r0 + mi * 16;
#pragma unroll
        for (int kk = 0; kk < 2; ++kk) a[mi][kk] = LDSW(A, rA, kk * 4 + kq);
    }
#pragma unroll
    for (int ni = 0; ni < 4; ++ni) {
        int rB = ni * 16 + (lane & 15);
#pragma unroll
        for (int kk = 0; kk < 2; ++kk) b[ni][kk] = LDSW(B, rB, kk * 4 + kq);
    }
#pragma unroll
    for (int kk = 0; kk < 2; ++kk)
#pragma unroll
        for (int mi = 0; mi < 2; ++mi)
#pragma unroll
            for (int ni = 0; ni < 4; ++ni)
                acc[mi][ni] = __builtin_amdgcn_mfma_f32_16x16x32_bf16(
                    a[mi][kk], b[ni][kk], acc[mi][ni], 0, 0, 0);
}

template <int NT, typename F>
__device__ __forceinline__ void run_pipeline(F tadr, bf16 (*As)[8192],
                                             bf16 (*Bs)[4096], f32x4 acc[2][4],
                                             int t, int lane, int wv) {
    {
        const bf16 *Ag, *Bg; int lda, ldb;
        tadr(0, Ag, lda, Bg, ldb);
        stageA4(Ag, lda, As[0], t);
        stageB2(Bg, ldb, Bs[0], t);
        if (NT > 1) {
            tadr(1, Ag, lda, Bg, ldb);
            stageA4(Ag, lda, As[1], t);
            stageB2(Bg, ldb, Bs[1], t);
        }
    }
    int cur = 0, pre = 2;
#pragma unroll 1
    for (int i = 0; i < NT; ++i) {
        if (i + 2 < NT) {
            const bf16 *Ag, *Bg; int lda, ldb;
            tadr(i + 2, Ag, lda, Bg, ldb);
            stageA4(Ag, lda, As[pre], t);
            stageB2(Bg, ldb, Bs[pre], t);
            asm volatile("s_waitcnt vmcnt(12)" ::: "memory");
        } else if (i + 1 < NT) {
            asm volatile("s_waitcnt vmcnt(6)" ::: "memory");
        } else {
            asm volatile("s_waitcnt vmcnt(0)" ::: "memory");
        }
        __builtin_amdgcn_s_barrier();
        __builtin_amdgcn_s_setprio(1);
        mma_tile(As[cur], Bs[cur], acc, lane, wv);
        __builtin_amdgcn_s_setprio(0);
        __builtin_amdgcn_s_barrier();
        cur = (cur == 2) ? 0 : cur + 1;
        pre = (pre == 2) ? 0 : pre + 1;
    }
}

// ---------- fc_in GEMM: h0 = x @ fcw^T + b ----------
__launch_bounds__(256, 2)
__global__ void gemm_fcin(const bf16* __restrict__ xb, const bf16* __restrict__ fcwb,
                          const float* __restrict__ fcb,
                          bf16* __restrict__ hb, bf16* __restrict__ hT,
                          bf16* __restrict__ hloT) {
    __shared__ __align__(16) bf16 As[3][8192];
    __shared__ __align__(16) bf16 Bs[3][4096];
    int t = threadIdx.x, lane = t & 63, wv = t >> 6;
    int row0 = blockIdx.y * 128;   // flattened b*1024+n
    int col0 = blockIdx.x * 64;
    f32x4 acc[2][4] = {};
    const bf16* Ab = xb + (size_t)row0 * 256;
    const bf16* Bb = fcwb + (size_t)col0 * 256;
    auto tadr = [&](int i, const bf16*& Ag, int& lda, const bf16*& Bg, int& ldb) {
        Ag = Ab + i * 64; lda = 256;
        Bg = Bb + i * 64; ldb = 256;
    };
    run_pipeline<4>(tadr, As, Bs, acc, t, lane, wv);

    int rbase = row0 + wv * 32 + ((lane >> 4) << 2);
    int cbase = col0 + (lane & 15);
#pragma unroll
    for (int mi = 0; mi < 2; ++mi) {
        int rg = rbase + mi * 16;
#pragma unroll
        for (int ni = 0; ni < 4; ++ni) {
            int col = cbase + ni * 16;
            float bias = fcb[col];
            bf16x4 tv, lv;
#pragma unroll
            for (int r = 0; r < 4; ++r) {
                float v = acc[mi][ni][r] + bias;
                size_t idx = (size_t)(rg + r) * 256 + col;
                bf16 hi = (bf16)v;
                hb[idx] = hi;
                tv[r] = hi;
                lv[r] = (bf16)(v - (float)hi);
            }
            int b = rg >> 10, n = rg & 1023;
            size_t tb = (((size_t)(b * 256 + col)) << 10) + n;
            *(bf16x4*)&hT[tb] = tv;
            *(bf16x4*)&hloT[tb] = lv;
        }
    }
}

// -- fused Euler step: 128x128, dbuf LDS, one barrier/window, ILP'd MMA --
template <bool LAST>
__launch_bounds__(256, 2)
__global__ void gemm_step(const bf16* __restrict__ adjb, const bf16* __restrict__ hbp,
                          const bf16* __restrict__ hTp, const bf16* __restrict__ weffT,
                          const float* __restrict__ ahs, const bf16* __restrict__ xT,
                          bf16* __restrict__ hloT, bf16* __restrict__ hbn,
                          bf16* __restrict__ hTn, float* __restrict__ out) {
    __shared__ __align__(16) char smem[65536];
    bf16 (*As)[8192] = (bf16(*)[8192])smem;              // 2 x 16 KB
    bf16 (*Bs)[8192] = (bf16(*)[8192])(smem + 32768);    // 2 x 16 KB
    int t = threadIdx.x, lane = t & 63, wv = t >> 6;
    int wm = wv >> 1, wn = wv & 1;
    // grid 512 = 32 b x (8 n-tiles x 2 d-tiles); batch keyed to XCD.
    int g = blockIdx.x;
    int xcd = g & 7, rest = g >> 3;
    int b = (rest & 3) * 8 + xcd;
    int tile = rest >> 2;
    int n0 = (tile & 7) * 128;
    int d0 = (tile >> 3) * 128;
    f32x4 acc[4][4] = {};

    // Anti-phase skew: odd blocks on a CU start ~2K cycles late so the two
    // co-resident blocks stall out-of-phase instead of in lockstep.
    if ((g >> 3) & 1) {
        __builtin_amdgcn_s_sleep(15);
        __builtin_amdgcn_s_sleep(15);
    }

    const bf16* A1 = adjb + (size_t)n0 * 1024;                // K=1024, 16 tiles
    const bf16* B1 = hTp + ((size_t)(b * 256 + d0)) * 1024;
    const bf16* A2 = hbp + ((size_t)(b * 1024 + n0)) * 256;   // K=256, 4 tiles
    const bf16* B2 = weffT + (size_t)d0 * 256;

    const int l15 = lane & 15, kq = lane >> 4;
    int rA[4], rB[4];
#pragma unroll
    for (int j = 0; j < 4; ++j) {
        rA[j] = wm * 64 + j * 16 + l15;
        rB[j] = wn * 64 + j * 16 + l15;
    }

    // prologue: stage tile 0
    stage<1024>(A1, As[0], t);
    stage<1024>(B1, Bs[0], t);

#pragma unroll 1
    for (int i = 0; i < 20; ++i) {
        asm volatile("s_waitcnt vmcnt(0)" ::: "memory");
        __builtin_amdgcn_s_barrier();            // buf[i&1] published; prior
                                                 // reads closed (consumed by MFMA)
        if (i + 1 < 20) {                        // WAR-safe post-barrier staging
            if (i + 1 < 16) {
                stage<1024>(A1 + (i + 1) * 64, As[(i + 1) & 1], t);
                stage<1024>(B1 + (i + 1) * 64, Bs[(i + 1) & 1], t);
            } else {
                stage<256>(A2 + (i - 15) * 64, As[(i + 1) & 1], t);
                stage<256>(B2 + (i - 15) * 64, Bs[(i + 1) & 1], t);
            }
        }
        const bf16* A = As[i & 1];
        const bf16* B = Bs[i & 1];
        // ---- ILP'd MMA: all 16 fragment loads issued before any MFMA ----
        bf16x8 af[8], bg[8];
#pragma unroll
        for (int kk = 0; kk < 2; ++kk) {
            int kc = kk * 4 + kq;
#pragma unroll
            for (int j = 0; j < 4; ++j) bg[kk * 4 + j] = LDSW(B, rB[j], kc);
        }
#pragma unroll
        for (int kk = 0; kk < 2; ++kk) {
            int kc = kk * 4 + kq;
#pragma unroll
            for (int j = 0; j < 4; ++j) af[kk * 4 + j] = LDSW(A, rA[j], kc);
        }
        __builtin_amdgcn_sched_barrier(0);       // loads stay clustered above
#pragma unroll
        for (int kk = 0; kk < 2; ++kk)
#pragma unroll
            for (int mi = 0; mi < 4; ++mi)
#pragma unroll
                for (int ni = 0; ni < 4; ++ni)
                    acc[mi][ni] = __builtin_amdgcn_mfma_f32_16x16x32_bf16(
                        af[kk * 4 + mi], bg[kk * 4 + ni], acc[mi][ni], 0, 0, 0);
    }
    __builtin_amdgcn_s_barrier();                // close last MMA reads before
                                                 // epilogue overlays LDS

    // ---------------- epilogue (hT-layout vectorized) ----------------
    const float dt = 0.125f;
    const int lq = (lane >> 4) << 2;
    bf16* img = (bf16*)smem;            // [128 cols][PADN nodes] overlay (33.8 KB)
    const int PADN = 132;
#pragma unroll
    for (int mi = 0; mi < 4; ++mi) {
        int nl = wm * 64 + mi * 16 + lq;         // local node base (x4 aligned)
        int ng = n0 + nl;
        f32x4 av = *(const f32x4*)&ahs[ng];
#pragma unroll
        for (int ni = 0; ni < 4; ++ni) {
            int cl = wn * 64 + ni * 16 + l15;    // local col
            int cg = d0 + cl;
            size_t tb = (((size_t)(b * 256 + cg)) << 10) + ng;
            bf16x4 hp = *(const bf16x4*)&hTp[tb];
            bf16x4 lp = *(const bf16x4*)&hloT[tb];
            bf16x4 xp = *(const bf16x4*)&xT[tb];
            bf16x4 nhi, nlo;
#pragma unroll
            for (int r = 0; r < 4; ++r) {
                float hold = (float)hp[r] + (float)lp[r];
                float f = acc[mi][ni][r] - (av[r] + 1.0f) * hold + (float)xp[r];
                float hv = hold + dt * f;
                if (LAST) {
                    out[(((size_t)b << 10) + ng + r) * 256 + cg] = hv;
                } else {
                    bf16 hi2 = (bf16)hv;
                    nhi[r] = hi2;
                    nlo[r] = (bf16)(hv - (float)hi2);
                }
            }
            if (!LAST) {
                *(bf16x4*)&hTn[tb] = nhi;
                *(bf16x4*)&hloT[tb] = nlo;
                int nsw = nl ^ (((cl >> 3) & 7) << 2);
                *(bf16x4*)&img[cl * PADN + nsw] = nhi;
            }
        }
    }
    if (!LAST) {
        asm volatile("s_waitcnt lgkmcnt(0)" ::: "memory");
        __builtin_amdgcn_s_barrier();
        const u16* imgu = (const u16*)img;
#pragma unroll
        for (int P = 0; P < 8; ++P) {
            int chunk = P * 256 + t;
            int node = chunk >> 4;       // 0..127
            int c8 = chunk & 15;
            u16 v[8];
#pragma unroll
            for (int k = 0; k < 8; ++k) {
                int col = c8 * 8 + k;
                v[k] = imgu[col * PADN + (node ^ (((col >> 3) & 7) << 2))];
            }
            uint4 pk;
            pk.x = v[0] | ((unsigned)v[1] << 16);
            pk.y = v[2] | ((unsigned)v[3] << 16);
            pk.z = v[4] | ((unsigned)v[5] << 16);
            pk.w = v[6] | ((unsigned)v[7] << 16);
            *(uint4*)&hbn[(((size_t)b << 10) + n0 + node) * 256 + d0 + c8 * 8] = pk;
        }
    }
}

extern "C" void kernel_launch(void* const* d_in, const int* in_sizes, int n_in,
                              void* d_out, int out_size, void* d_ws, size_t ws_size,
                              hipStream_t stream) {
    const float* x     = (const float*)d_in[0];
    const float* adj   = (const float*)d_in[1];
    const float* alpha = (const float*)d_in[2];
    const float* w     = (const float*)d_in[3];
    const float* dvec  = (const float*)d_in[4];
    const float* fcw   = (const float*)d_in[5];
    const float* fcb   = (const float*)d_in[6];
    float* out = (float*)d_out;   // fp32 h, written by the LAST step only

    const size_t HB = (size_t)32 * 1024 * 256 * 2;  // 16 MiB
    char* p = (char*)d_ws;
    bf16* hb0   = (bf16*)p; p += HB;
    bf16* hb1   = (bf16*)p; p += HB;
    bf16* hT0   = (bf16*)p; p += HB;
    bf16* hT1   = (bf16*)p; p += HB;
    bf16* xb    = (bf16*)p; p += HB;
    bf16* hloT  = (bf16*)p; p += HB;
    bf16* xT    = (bf16*)p; p += HB;
    bf16* adjb  = (bf16*)p; p += (size_t)1024 * 1024 * 2;
    bf16* fcwb  = (bf16*)p; p += 256 * 256 * 2;
    bf16* weffT = (bf16*)p; p += 256 * 256 * 2;
    float* ahs  = (float*)p; p += 1024 * 4;

    prep_alpha<<<4, 256, 0, stream>>>(alpha, ahs);
    prep_adj<<<1024, 256, 0, stream>>>(adj, ahs, adjb);
    prep_weff<<<256, 256, 0, stream>>>(w, dvec, weffT);
    prep_xT<<<dim3(16, 4, 32), 256, 0, stream>>>(x, xT, xb);
    cast_f32_bf16x4<<<64, 256, 0, stream>>>(fcw, fcwb, 16384);

    gemm_fcin<<<dim3(4, 256), 256, 0, stream>>>(xb, fcwb, fcb, hb0, hT0, hloT);

    bf16* hb[2] = {hb0, hb1};
    bf16* hT[2] = {hT0, hT1};
    int cur = 0;
    for (int s = 0; s < 8; ++s) {
        if (s < 7)
            gemm_step<false><<<512, 256, 0, stream>>>(
                adjb, hb[cur], hT[cur], weffT, ahs, xT, hloT,
                hb[cur ^ 1], hT[cur ^ 1], out);
        else
            gemm_step<true><<<512, 256, 0, stream>>>(
                adjb, hb[cur], hT[cur], weffT, ahs, xT, hloT,
                hb[cur ^ 1], hT[cur ^ 1], out);
        cur ^= 1;
    }
}